// Round 4
// baseline (774.614 us; speedup 1.0000x reference)
//
#include <hip/hip_runtime.h>
#include <math.h>

#define NWAY 5
#define NSUP 25
#define NZV  125
#define DF   640
#define NQ   75
#define TPB  640   // two batches per block: waves 0-4 batch A, 5-9 batch B
#define CHW  128   // staging chunk width (columns)
#define GSTR 132   // GBUF row stride in floats
#define MST  27    // Msh row stride in doubles (25+2 pad: 2-way banks, free)

// =====================================================================
// Fast transform: tf(x) = sign(x) * (g(|x|+1e-5) - g(1e-5)),
//   g(t) = ln(1/t+1)^{-1.3} = exp2(-1.3*log2(log2(1/t+1)) + A).
// =====================================================================
__device__ __forceinline__ float gfun(float t) {
  const float l2 = __log2f(__builtin_amdgcn_rcpf(t) + 1.0f);
  return __builtin_amdgcn_exp2f(fmaf(-1.3f, __log2f(l2), 0.68739628f));
}
__device__ __forceinline__ float simple_tf(float x, float Cg) {
  const float s = gfun(fabsf(x) + 1e-5f) - Cg;
  return (x >= 0.0f) ? s : -s;
}

// Fast fp64 reciprocal: v_rcp_f64 + 2 Newton -> full fp64 (validated:
// absmax unchanged vs exact divide). Inputs strictly positive.
__device__ __forceinline__ double fdrcp(double d) {
  double r;
  asm("v_rcp_f64 %0, %1" : "=v"(r) : "v"(d));
  r = r * fma(-d, r, 2.0);
  r = r * fma(-d, r, 2.0);
  return r;
}

// Constant-lane fp64 broadcast via v_readlane (VALU, off the LDS pipe).
__device__ __forceinline__ double bcastd(double v, const int srclane) {
  const int lo = __builtin_amdgcn_readlane(__double2loint(v), srclane);
  const int hi = __builtin_amdgcn_readlane(__double2hiint(v), srclane);
  return __hiloint2double(hi, lo);
}

// In-place Gauss-Jordan of 25x25 SPD; rows live on lanes BASE..BASE+24.
template <int BASE, int J>
__device__ __forceinline__ void gjp(double (&a)[25], const int lane,
                                    const bool act) {
  const double djj = bcastd(a[J], BASE + J);
  const double pinv = fdrcp(djj);
  if (act) a[J] = ((lane == BASE + J) ? 1.0 : a[J]) * pinv;
#pragma unroll
  for (int r = 0; r < 25; ++r) {
    if (r != J) {
      const double f = bcastd(a[r], BASE + J);
      if (act) a[r] = ((lane == BASE + J) ? 0.0 : a[r]) - f * a[J];
    }
  }
}
template <int BASE, int J = 0>
__device__ __forceinline__ void gjall(double (&a)[25], const int lane,
                                      const bool act) {
  if constexpr (J < 25) {
    gjp<BASE, J>(a, lane, act);
    gjall<BASE, J + 1>(a, lane, act);
  }
}

// stage CHW columns of RAW transformed train rows into GBUF[25][GSTR].
__device__ __forceinline__ void stage_chunk(const float* __restrict__ tb,
                                            const int ch, const bool us,
                                            const float Cg, float* GBUF,
                                            const int tl) {
  for (int idx = tl; idx < NSUP * CHW; idx += 320) {
    const int r = idx >> 7, cc = idx & (CHW - 1);
    float v = tb[r * DF + ch * CHW + cc];
    if (us) v = simple_tf(v, Cg);
    GBUF[r * GSTR + cc] = v;
  }
}

// =====================================================================
// qp_kernel v4: column-ownership layout. Thread (wave w, lane l<25)
// owns index v = l*5+w of every 125-vector. All slice work (tt,c1,vv,
// dd,di,rsc,dx/ds/dz, state updates) is wave-local: in-wave LDS
// round-trips need NO barrier (program order + compiler lgkmcnt).
// Cross-wave sync only at: reductions, Hs gather, dyw broadcast,
// alpha-min combines -> ~10 barriers/iter vs ~30 before (~50 total vs
// ~120), and every phase engages all waves. Init exploits dd==1:
// Winv = (M+I)/5 analytically (one wave-0 GJ deleted). All sync is
// plain __syncthreads (flag-barrier/atomic variants measured-negative).
// =====================================================================
__global__ void __launch_bounds__(TPB, 3) qp_kernel(
    const float* __restrict__ train, const int* __restrict__ usimple,
    float* __restrict__ xfg, const int B) {
  const int tid = threadIdx.x;
  const int half = tid >= 320 ? 1 : 0;
  const int tl = tid - 320 * half;
  const int lane = tid & 63;
  const int w = tl >> 6;
  const bool own = lane < 25;
  const int v = lane * 5 + w;  // owned index (meaningful when own)
  const int bb = 2 * blockIdx.x + half;
  const bool live = bb < B;
  const bool us = (usimple[0] != 0);
  const float Cg = gfun(1e-5f);

  // Per-half LDS pool (doubles). 2*5008*8 = 80128 B.
  __shared__ __align__(16) double POOL[2][5008];
  double* ph = POOL[half];
  double* Msh = ph;            // 675  (25 rows, stride 27)
  double* Hs  = ph + 675;      // 3125 (Hinv_k dump; GBUF overlays)
  double* x   = ph + 3800;     // 125
  double* sv  = ph + 3925;     // 125
  double* zv  = ph + 4050;     // 125
  double* tt  = ph + 4175;     // 125
  double* c1  = ph + 4300;     // 125
  double* vv  = ph + 4425;     // 125
  double* rx  = ph + 4550;     // 125
  double* rz  = ph + 4675;     // 125
  double* yv  = ph + 4800;     // 25
  double* gg  = ph + 4825;     // 25
  double* dyw = ph + 4850;     // 25
  double* dnv = ph + 4875;     // 25
  double* SC  = ph + 4900;     // 32
  float*  bxs = (float*)(ph + 4932);   // 125 floats
  float*  invn = (float*)(ph + 4995);  // 25 floats
  float*  GBUF = (float*)Hs;           // 25*132 floats (Gram/phase-4)

  double hv[25];  // lanes 0-24: row `lane` of Hinv_w; wave0 lanes 32-56:
                  // row lane-32 of Winv (disjoint lanes share the regs)
  const float* tb = train + (size_t)(live ? bb : 0) * NSUP * DF;

  // ---- Gram: G = F F^T, fp64 accumulate, CHW-wide LDS chunks ----
  int i1, j1, i2v = 0, j2v = 0;
  {
    int rem = tl, i = 0;
    while (rem >= NSUP - i) { rem -= NSUP - i; ++i; }
    i1 = i; j1 = i + rem;
  }
  if (tl < 5) {
    int rem = 320 + tl, i = 0;
    while (rem >= NSUP - i) { rem -= NSUP - i; ++i; }
    i2v = i; j2v = i + rem;
  }
  double acc1 = 0.0, acc2 = 0.0;
  for (int ch = 0; ch < DF / CHW; ++ch) {
    stage_chunk(tb, ch, us, Cg, GBUF, tl);
    __syncthreads();
    {
      const float4* ra = (const float4*)(GBUF + i1 * GSTR);
      const float4* rb = (const float4*)(GBUF + j1 * GSTR);
#pragma unroll
      for (int c = 0; c < CHW / 4; ++c) {
        float4 av = ra[c], bv = rb[c];
        acc1 += (double)av.x * bv.x + (double)av.y * bv.y +
                (double)av.z * bv.z + (double)av.w * bv.w;
      }
    }
    if (tl < 5) {
      const float4* ra = (const float4*)(GBUF + i2v * GSTR);
      const float4* rb = (const float4*)(GBUF + j2v * GSTR);
#pragma unroll
      for (int c = 0; c < CHW / 4; ++c) {
        float4 av = ra[c], bv = rb[c];
        acc2 += (double)av.x * bv.x + (double)av.y * bv.y +
                (double)av.z * bv.z + (double)av.w * bv.w;
      }
    }
    __syncthreads();
  }
  Msh[i1 * MST + j1] = acc1;
  if (i1 != j1) Msh[j1 * MST + i1] = acc1;
  if (tl < 5) {
    Msh[i2v * MST + j2v] = acc2;
    if (i2v != j2v) Msh[j2v * MST + i2v] = acc2;
  }
  __syncthreads();

  // ---- norms from Gram diagonal; scale M = D G D + I ----
  if (tl < 25) {
    const double g = Msh[tl * MST + tl];
    const double dn = 1.0 / fmax(sqrt(g), 1e-12);
    dnv[tl] = dn;
    invn[tl] = (float)dn;
  }
  __syncthreads();
  for (int idx = tl; idx < 25 * MST; idx += 320) {
    const int i = idx / MST, j = idx - i * MST;
    if (j < 25) {
      double vm = Msh[idx] * dnv[i] * dnv[j];
      if (i == j) vm += 1.0;
      Msh[idx] = vm;
    }
  }
  __syncthreads();

  // ---- init factorize: dd==1 -> H = M+I identical on all waves ----
  if (own) {
#pragma unroll
    for (int j = 0; j < 25; ++j)
      hv[j] = Msh[lane * MST + j] + ((j == lane) ? 1.0 : 0.0);
  }
  gjall<0>(hv, lane, own);

  // ---- init solve (rs=0, dd=di=1; Winv = (M+I)/5 analytically) ----
  const double oh = (own && w == (lane % 5)) ? 1.0 : 0.0;
  double ttv = 0.0, vvv = 0.0;
  if (own) {
    ttv = -0.1 * oh;          // rz
    tt[v] = ttv;
    double acc = oh;          // -rx
#pragma unroll
    for (int j = 0; j < 25; ++j) acc += Msh[lane * MST + j] * tt[j * 5 + w];
    c1[v] = acc;
    double a2 = 0.0;
#pragma unroll
    for (int j = 0; j < 25; ++j) a2 += hv[j] * c1[j * 5 + w];
    vvv = a2;
    vv[v] = a2;
  }
  __syncthreads();
  double yvr = 0.0;  // y owner: wave0 lanes 32-56
  if (w == 0) {
    if (lane < 25) {
      double c2v = 0.0, ggv = 0.0;   // ry = 0 at init
#pragma unroll
      for (int k = 0; k < 5; ++k) { c2v += tt[lane * 5 + k]; ggv += vv[lane * 5 + k]; }
      gg[lane] = ggv - c2v;
    }
    if (lane >= 32 && lane < 57) {
      const int i = lane - 32;
      double acc = gg[i];            // (M+I)*gg
#pragma unroll
      for (int j = 0; j < 25; ++j) acc += Msh[i * MST + j] * gg[j];
      const double dyv = 0.2 * acc;  // Winv = (M+I)/5
      dyw[i] = dyv;
      yv[i] = dyv;
      yvr = dyv;
    }
  }
  __syncthreads();
  double xo = 0.0, so = 0.0, zo = 0.0;
  if (own) {
    double corr = 0.0;
#pragma unroll
    for (int j = 0; j < 25; ++j) corr += hv[j] * dyw[j];
    const double u = vvv - corr;     // dd=1: dz=u; dx=u-tt; ds=-dz
    zo = u;
    xo = u - ttv;
    so = -u;
    x[v] = xo; sv[v] = so; zv[v] = zo;
  }
  __syncthreads();
  if (w == 0) {  // both shift-mins in one pass
    double m1 = 1e300, m2 = 1e300;
    for (int m = lane; m < 125; m += 64) { m1 = fmin(m1, sv[m]); m2 = fmin(m2, zv[m]); }
#pragma unroll
    for (int off = 32; off > 0; off >>= 1) {
      m1 = fmin(m1, __shfl_xor(m1, off));
      m2 = fmin(m2, __shfl_xor(m2, off));
    }
    if (lane == 0) { SC[6] = m1; SC[7] = m2; }
  }
  __syncthreads();
  if (own) {
    const double ms = SC[6], mz = SC[7];
    if (ms < 0.0) { so -= (ms - 1.0); sv[v] = so; }
    if (mz < 0.0) { zo -= (mz - 1.0); zv[v] = zo; }
  }

  double best_res = 1e300;
  double ddv = 1.0, div = 1.0;
  double dyt = 0.0;

#pragma unroll 1
  for (int it = 0; it < 3; ++it) {
    __syncthreads();                               // B1: state visible
    // residual (wave-local per column)
    double rxv = 0.0, rzv = 0.0, ryv = 0.0;
    if (own) {
      double acc = yv[lane] + zo - oh;
#pragma unroll
      for (int j = 0; j < 25; ++j) acc += Msh[lane * MST + j] * x[j * 5 + w];
      rxv = acc;
      rzv = xo + so - 0.1 * oh;
      rx[v] = rxv;
      rz[v] = rzv;
    }
    if (w == 0 && lane < 25) {
#pragma unroll
      for (int k = 0; k < 5; ++k) ryv += x[lane * 5 + k];
    }
    __syncthreads();                               // B2
    if (w == 0) {  // consolidated reduction
      double s1 = 0, s2 = 0, s3 = 0, s4 = ryv * ryv;
      for (int m = lane; m < 125; m += 64) {
        s1 += sv[m] * zv[m];
        s2 += rx[m] * rx[m];
        s3 += rz[m] * rz[m];
      }
#pragma unroll
      for (int off = 32; off > 0; off >>= 1) {
        s1 += __shfl_xor(s1, off);
        s2 += __shfl_xor(s2, off);
        s3 += __shfl_xor(s3, off);
        s4 += __shfl_xor(s4, off);
      }
      if (lane == 0) { SC[2] = s1; SC[3] = s2; SC[4] = s3; SC[5] = s4; }
    }
    __syncthreads();                               // B3
    const double szsum = SC[2];
    const double mu = fabs(szsum) / 125.0;
    const double res = sqrt(SC[4] + 1e-30) + sqrt(SC[5] + 1e-30) +
                       sqrt(SC[3] + 1e-30) + 125.0 * mu;
    if (res < best_res) {  // uniform across threads
      best_res = res;
      if (own) bxs[v] = (float)xo;
    }
    if (it == 2) break;

    // dd/di in registers; Hinv_w per wave; dump to Hs for wave0
    if (own) {
      ddv = zo * fdrcp(so);
      div = so * fdrcp(zo);
#pragma unroll
      for (int j = 0; j < 25; ++j)
        hv[j] = Msh[lane * MST + j] + ((j == lane) ? ddv : 0.0);
    }
    gjall<0>(hv, lane, own);
    if (own) {
#pragma unroll
      for (int j = 0; j < 25; ++j) Hs[(w * 25 + lane) * 25 + j] = hv[j];
    }
    // affine phase A (wave-local): tt = rz - s (rs=z, z*di=s)
    double dxa_ = 0.0, dsa_ = 0.0, dza_ = 0.0;
    if (own) {
      ttv = rzv - so;
      tt[v] = ttv;
      double acc = -rxv;
#pragma unroll
      for (int j = 0; j < 25; ++j) acc += Msh[lane * MST + j] * tt[j * 5 + w];
      c1[v] = acc;
      double a2 = 0.0;
#pragma unroll
      for (int j = 0; j < 25; ++j) a2 += hv[j] * c1[j * 5 + w];
      vvv = a2;
      vv[v] = a2;
    }
    __syncthreads();                               // B4
    if (w == 0) {  // c2/gg on lanes 0-24; W gather + GJ on lanes 32-56
      if (lane < 25) {
        double c2v = -ryv, ggv = 0.0;
#pragma unroll
        for (int k = 0; k < 5; ++k) { c2v += tt[lane * 5 + k]; ggv += vv[lane * 5 + k]; }
        gg[lane] = ggv - c2v;
      }
      if (lane >= 32 && lane < 57) {
        const int i = lane - 32;
#pragma unroll
        for (int r = 0; r < 25; ++r) {
          double a = 0.0;
#pragma unroll
          for (int k = 0; k < 5; ++k) a += Hs[(k * 25 + i) * 25 + r];
          hv[r] = a;  // W row i (lanes 32-56 share hv regs with Hinv)
        }
      }
      gjall<32>(hv, lane, lane >= 32 && lane < 57);
      if (lane >= 32 && lane < 57) {
        const int i = lane - 32;
        double acc = 0.0;
#pragma unroll
        for (int r = 0; r < 25; ++r) acc += hv[r] * gg[r];
        dyw[i] = acc;
        dyt = acc;
      }
    }
    __syncthreads();                               // B5
    if (own) {  // phase C affine
      double corr = 0.0;
#pragma unroll
      for (int j = 0; j < 25; ++j) corr += hv[j] * dyw[j];
      const double u = vvv - corr;
      dza_ = ddv * u;
      dxa_ = u - ttv;
      dsa_ = (-zo - dza_) * div;
    }
    double am = 1e12;
    if (own) {
      const double a1 = (dza_ < 0.0) ? (-zo / dza_) : 1e12;
      const double a2 = (dsa_ < 0.0) ? (-so / dsa_) : 1e12;
      am = fmin(a1, a2);
    }
#pragma unroll
    for (int off = 32; off > 0; off >>= 1) am = fmin(am, __shfl_xor(am, off));
    if (lane == 0) SC[8 + w] = am;
    __syncthreads();                               // B6
    const double aff = fmin(fmin(fmin(SC[8], SC[9]), fmin(SC[10], SC[11])),
                            fmin(SC[12], 1.0));
    double tp = 0.0;
    if (own) tp = (so + aff * dsa_) * (zo + aff * dza_);
#pragma unroll
    for (int off = 32; off > 0; off >>= 1) tp += __shfl_xor(tp, off);
    if (lane == 0) SC[16 + w] = tp;
    __syncthreads();                               // B7
    const double num = SC[16] + SC[17] + SC[18] + SC[19] + SC[20];
    const double sg = num / szsum;
    const double musig = mu * (sg * sg * sg);
    // corrector phase A (ZR: rx=rz=ry=0, rs=rsc)
    double rscv = 0.0, tt2v = 0.0, vvv2 = 0.0;
    if (own) {
      rscv = (-musig + dsa_ * dza_) * fdrcp(so);
      tt2v = -rscv * div;
      tt[v] = tt2v;
      double acc = 0.0;
#pragma unroll
      for (int j = 0; j < 25; ++j) acc += Msh[lane * MST + j] * tt[j * 5 + w];
      c1[v] = acc;
      double a2 = 0.0;
#pragma unroll
      for (int j = 0; j < 25; ++j) a2 += hv[j] * c1[j * 5 + w];
      vvv2 = a2;
      vv[v] = a2;
    }
    __syncthreads();                               // B8
    if (w == 0) {
      if (lane < 25) {
        double c2v = 0.0, ggv = 0.0;
#pragma unroll
        for (int k = 0; k < 5; ++k) { c2v += tt[lane * 5 + k]; ggv += vv[lane * 5 + k]; }
        gg[lane] = ggv - c2v;
      }
      if (lane >= 32 && lane < 57) {  // Winv still in hv
        const int i = lane - 32;
        double acc = 0.0;
#pragma unroll
        for (int r = 0; r < 25; ++r) acc += hv[r] * gg[r];
        dyw[i] = acc;
        dyt += acc;
      }
    }
    __syncthreads();                               // B9
    double dxT = 0.0, dsT = 0.0, dzT = 0.0;
    if (own) {  // phase C corrector + totals
      double corr = 0.0;
#pragma unroll
      for (int j = 0; j < 25; ++j) corr += hv[j] * dyw[j];
      const double u = vvv2 - corr;
      const double dzc = ddv * u;
      dzT = dza_ + dzc;
      dxT = dxa_ + (u - tt2v);
      dsT = dsa_ + (-rscv - dzc) * div;
    }
    am = 1e12;
    if (own) {
      const double a1 = (dzT < 0.0) ? (-zo / dzT) : 1e12;
      const double a2 = (dsT < 0.0) ? (-so / dsT) : 1e12;
      am = fmin(a1, a2);
    }
#pragma unroll
    for (int off = 32; off > 0; off >>= 1) am = fmin(am, __shfl_xor(am, off));
    if (lane == 0) SC[8 + w] = am;
    __syncthreads();                               // B10
    const double al =
        fmin(0.999 * fmin(fmin(fmin(SC[8], SC[9]), fmin(SC[10], SC[11])),
                          SC[12]),
             1.0);
    if (own) {
      xo += al * dxT;
      so += al * dsT;
      zo += al * dzT;
      x[v] = xo; sv[v] = so; zv[v] = zo;
    }
    if (w == 0 && lane >= 32 && lane < 57) {
      yvr += al * dyt;
      yv[lane - 32] = yvr;
    }
  }
  __syncthreads();

  // ---- phase 4: xfg[w][d] = sum_s (bx[s,w]*invn[s]) * Fraw[s][d] ----
  // bxs column w was written by wave w's own lanes -> in-wave reads, no
  // barrier. GBUF overlays Hs (dead after last factorize).
  float xs[25];
#pragma unroll
  for (int s_ = 0; s_ < 25; ++s_) xs[s_] = bxs[s_ * 5 + w] * invn[s_];
  for (int ch = 0; ch < DF / CHW; ++ch) {
    stage_chunk(tb, ch, us, Cg, GBUF, tl);
    __syncthreads();
    float accA = 0.0f, accB = 0.0f;
#pragma unroll
    for (int s_ = 0; s_ < 25; ++s_) {
      accA += xs[s_] * GBUF[s_ * GSTR + lane];
      accB += xs[s_] * GBUF[s_ * GSTR + 64 + lane];
    }
    if (live) {
      float* op = xfg + ((size_t)bb * NWAY + w) * DF + ch * CHW;
      op[lane] = accA;
      op[64 + lane] = accB;
    }
    __syncthreads();
  }
}

// =====================================================================
// Output kernel: one block per batch, 640 threads = 10 waves; wave u
// handles queries u, u+10, ... float4 loads (3/query).
// =====================================================================
__global__ void __launch_bounds__(640) out_kernel(
    const float* __restrict__ test, const int* __restrict__ usimple,
    const float* __restrict__ xfg, float* __restrict__ out) {
  const int b = blockIdx.x;
  const int tid = threadIdx.x;
  const int lane = tid & 63;
  const int u = tid >> 6;   // 0..9
  const bool us = (usimple[0] != 0);
  const float Cg = gfun(1e-5f);

  __shared__ float xfs[NWAY * DF];
  for (int i = tid; i < NWAY * DF; i += 640)
    xfs[i] = xfg[(size_t)b * NWAY * DF + i];
  __syncthreads();
  const float4* xf4 = (const float4*)xfs;

  const float* qb = test + (size_t)b * NQ * DF;
#pragma unroll 2
  for (int jj = 0; jj < 8; ++jj) {
    const int q = u + 10 * jj;
    if (q >= NQ) break;
    const float4* qr4 = (const float4*)(qb + (size_t)q * DF);
    float nrm = 0.0f, a0 = 0.0f, a1 = 0.0f, a2 = 0.0f, a3 = 0.0f, a4 = 0.0f;
#pragma unroll
    for (int c = 0; c < 3; ++c) {
      if (c < 2 || lane < 32) {
        const int f4i = lane + 64 * c;
        float4 vq = qr4[f4i];
        if (us) {
          vq.x = simple_tf(vq.x, Cg);
          vq.y = simple_tf(vq.y, Cg);
          vq.z = simple_tf(vq.z, Cg);
          vq.w = simple_tf(vq.w, Cg);
        }
        nrm += vq.x * vq.x + vq.y * vq.y + vq.z * vq.z + vq.w * vq.w;
        float4 t;
        t = xf4[0 * (DF / 4) + f4i];
        a0 += vq.x * t.x + vq.y * t.y + vq.z * t.z + vq.w * t.w;
        t = xf4[1 * (DF / 4) + f4i];
        a1 += vq.x * t.x + vq.y * t.y + vq.z * t.z + vq.w * t.w;
        t = xf4[2 * (DF / 4) + f4i];
        a2 += vq.x * t.x + vq.y * t.y + vq.z * t.z + vq.w * t.w;
        t = xf4[3 * (DF / 4) + f4i];
        a3 += vq.x * t.x + vq.y * t.y + vq.z * t.z + vq.w * t.w;
        t = xf4[4 * (DF / 4) + f4i];
        a4 += vq.x * t.x + vq.y * t.y + vq.z * t.z + vq.w * t.w;
      }
    }
#pragma unroll
    for (int off = 32; off > 0; off >>= 1) {
      nrm += __shfl_xor(nrm, off);
      a0 += __shfl_xor(a0, off);
      a1 += __shfl_xor(a1, off);
      a2 += __shfl_xor(a2, off);
      a3 += __shfl_xor(a3, off);
      a4 += __shfl_xor(a4, off);
    }
    if (lane == 0) {
      const float sc = 1.0f / fmaxf(sqrtf(nrm), 1e-12f);
      float* op = out + ((size_t)b * NQ + q) * 5;
      op[0] = a0 * sc;
      op[1] = a1 * sc;
      op[2] = a2 * sc;
      op[3] = a3 * sc;
      op[4] = a4 * sc;
    }
  }
}

// =====================================================================
extern "C" void kernel_launch(void* const* d_in, const int* in_sizes, int n_in,
                              void* d_out, int out_size, void* d_ws,
                              size_t ws_size, hipStream_t stream) {
  const float* ftest = (const float*)d_in[0];
  const float* ftrain = (const float*)d_in[1];
  const int* usimple = (const int*)d_in[4];
  float* out = (float*)d_out;
  const int B = in_sizes[1] / (NSUP * DF);

  float* xfg = (float*)d_ws;  // B * 5 * 640 floats

  qp_kernel<<<dim3((B + 1) / 2), dim3(TPB), 0, stream>>>(ftrain, usimple,
                                                         xfg, B);
  out_kernel<<<dim3(B), dim3(640), 0, stream>>>(ftest, usimple, xfg, out);
}

// Round 5
// 441.885 us; speedup vs baseline: 1.7530x; 1.7530x over previous
//
#include <hip/hip_runtime.h>
#include <math.h>

#define NWAY 5
#define NSUP 25
#define NZV  125
#define DF   640
#define NQ   75
#define TPB  640   // two batches per block: waves 0-4 batch A, 5-9 batch B

// =====================================================================
// Fast transform: tf(x) = sign(x) * (g(|x|+1e-5) - g(1e-5)),
//   g(t) = ln(1/t+1)^{-1.3} = exp2(-1.3*log2(log2(1/t+1)) + A),
//   A = -1.3*log2(ln2) = 0.68739628. 4 transcendentals vs reference's 8.
// =====================================================================
__device__ __forceinline__ float gfun(float t) {
  const float l2 = __log2f(__builtin_amdgcn_rcpf(t) + 1.0f);
  return __builtin_amdgcn_exp2f(fmaf(-1.3f, __log2f(l2), 0.68739628f));
}
__device__ __forceinline__ float simple_tf(float x, float Cg) {
  const float s = gfun(fabsf(x) + 1e-5f) - Cg;
  return (x >= 0.0f) ? s : -s;
}

// Fast fp64 reciprocal: v_rcp_f64 + 2 Newton -> full fp64 accuracy
// (validated R2-R4: absmax bit-identical to exact divide). Inputs > 0.
__device__ __forceinline__ double fdrcp(double d) {
  double r;
  asm("v_rcp_f64 %0, %1" : "=v"(r) : "v"(d));
  r = r * fma(-d, r, 2.0);
  r = r * fma(-d, r, 2.0);
  return r;
}

// Constant-lane fp64 broadcast via v_readlane (VALU, off the LDS pipe).
__device__ __forceinline__ double bcastd(double v, const int srclane) {
  const int lo = __builtin_amdgcn_readlane(__double2loint(v), srclane);
  const int hi = __builtin_amdgcn_readlane(__double2hiint(v), srclane);
  return __hiloint2double(hi, lo);
}

// In-place Gauss-Jordan of 25x25 SPD; columns live on lanes BASE..BASE+24.
template <int BASE, int J>
__device__ __forceinline__ void gjp(double (&a)[25], const int lane,
                                    const bool act) {
  const double djj = bcastd(a[J], BASE + J);
  const double pinv = fdrcp(djj);
  if (act) a[J] = ((lane == BASE + J) ? 1.0 : a[J]) * pinv;
#pragma unroll
  for (int r = 0; r < 25; ++r) {
    if (r != J) {
      const double f = bcastd(a[r], BASE + J);
      if (act) a[r] = ((lane == BASE + J) ? 0.0 : a[r]) - f * a[J];
    }
  }
}
template <int BASE, int J = 0>
__device__ __forceinline__ void gjall(double (&a)[25], const int lane,
                                      const bool act) {
  if constexpr (J < 25) {
    gjp<BASE, J>(a, lane, act);
    gjall<BASE, J + 1>(a, lane, act);
  }
}

// Factorize (per half): hv <- row `lane` of Hinv_w; this half's wave-0
// lanes 32-56 additionally get Winv = (sum_k Hinv_k)^-1 rows.
// W accumulation: write-first sequential waves (5 barriers, no zero
// pass; atomic and flag-barrier variants were measured-negative).
__device__ __forceinline__ void factorize(const double* Msh, const double* dd,
                                          double* W, double (&hv)[25],
                                          const int tl, const int lane,
                                          const int w) {
  if (lane < 25) {
#pragma unroll
    for (int j = 0; j < 25; ++j)
      hv[j] = Msh[lane * 26 + j] + ((j == lane) ? dd[lane * 5 + w] : 0.0);
  }
  gjall<0>(hv, lane, true);
#pragma unroll
  for (int k = 0; k < 5; ++k) {
    if (w == k && lane < 25) {
      if (k == 0) {
#pragma unroll
        for (int j = 0; j < 25; ++j) W[lane * 26 + j] = hv[j];
      } else {
#pragma unroll
        for (int j = 0; j < 25; ++j) W[lane * 26 + j] += hv[j];
      }
    }
    __syncthreads();
  }
  if (w == 0) {
    if (lane >= 32 && lane < 57) {
#pragma unroll
      for (int r = 0; r < 25; ++r) hv[r] = W[(lane - 32) * 26 + r];
    }
    gjall<32>(hv, lane, lane >= 32 && lane < 57);
  }
  // next consumer phase begins with its own __syncthreads()
}

// KKT solve (per half). ZRS: rs==0; ZR: rx=rz=ry==0; ACC: accumulate.
// di = 1/dd precomputed -> the two per-solve divides become multiplies.
template <bool ZRS, bool ZR, bool ACC>
__device__ __forceinline__ void kkt_solve(
    const double* Msh, const double* dd, const double* di, double* tt,
    double* c1, double* c2, double* vv, double* gg, double* dyw,
    const double* rx, const double* rs, const double* rz, const double* ry,
    double (&hv)[25], double* dx, double* ds, double* dz, double* dy,
    const int tl, const int lane, const int w) {
  if (tl < NZV) {
    double t = ZR ? 0.0 : rz[tl];
    if (!ZRS) t -= rs[tl] * di[tl];
    tt[tl] = t;
  }
  __syncthreads();
  if (tl < NZV) {
    const int i = tl / 5, k = tl - i * 5;
    double acc = ZR ? 0.0 : -rx[tl];
#pragma unroll
    for (int j = 0; j < 25; ++j) acc += Msh[i * 26 + j] * tt[j * 5 + k];
    c1[tl] = acc;
  } else if (tl >= 128 && tl < 153) {
    const int i = tl - 128;
    double acc = ZR ? 0.0 : -ry[i];
#pragma unroll
    for (int k = 0; k < 5; ++k) acc += tt[i * 5 + k];
    c2[i] = acc;
  }
  __syncthreads();
  if (lane < 25) {
    double acc = 0.0;
#pragma unroll
    for (int j = 0; j < 25; ++j) acc += hv[j] * c1[j * 5 + w];
    vv[lane * 5 + w] = acc;
  }
  __syncthreads();
  if (w == 0) {  // gg then dy in the SAME wave: LDS program order suffices
    if (lane < 25) {
      double acc = -c2[lane];
#pragma unroll
      for (int k = 0; k < 5; ++k) acc += vv[lane * 5 + k];
      gg[lane] = acc;
    }
    if (lane >= 32 && lane < 57) {
      double acc = 0.0;
#pragma unroll
      for (int r = 0; r < 25; ++r) acc += hv[r] * gg[r];
      dyw[lane - 32] = acc;
      if (ACC) dy[lane - 32] += acc; else dy[lane - 32] = acc;
    }
  }
  __syncthreads();
  if (lane < 25) {
    double acc = 0.0;
#pragma unroll
    for (int j = 0; j < 25; ++j) acc += hv[j] * dyw[j];
    const int v = lane * 5 + w;
    const double u = vv[v] - acc;
    const double dzv = dd[v] * u;
    const double dxv = u - tt[v];
    const double dsv = ((ZRS ? 0.0 : -rs[v]) - dzv) * di[v];
    if (ACC) { dz[v] += dzv; dx[v] += dxv; ds[v] += dsv; }
    else     { dz[v]  = dzv; dx[v]  = dxv; ds[v]  = dsv; }
  }
  __syncthreads();
}

// Per-half block reduction: first wave of the half reduces buf[0..n).
__device__ __forceinline__ double bred(const double* buf, int n, int ismin,
                                       double* SCh, const int w,
                                       const int lane) {
  __syncthreads();
  if (w == 0) {
    double acc = ismin ? 1e300 : 0.0;
    for (int m = lane; m < n; m += 64) {
      const double v = buf[m];
      acc = ismin ? fmin(acc, v) : (acc + v);
    }
#pragma unroll
    for (int off = 32; off > 0; off >>= 1) {
      const double o = __shfl_xor(acc, off);
      acc = ismin ? fmin(acc, o) : (acc + o);
    }
    if (lane == 0) SCh[15] = acc;
  }
  __syncthreads();
  return SCh[15];
}

// stage 64 columns of RAW transformed train rows into GBUF[25][68].
// (Normalization folded into M-rescale and phase-4 weights.)
__device__ __forceinline__ void stage_chunk(const float* __restrict__ tb,
                                            const int ch, const bool us,
                                            const float Cg, float* GBUF,
                                            const int tl) {
  for (int idx = tl; idx < 1600; idx += 320) {
    const int r = idx >> 6, cc = idx & 63;
    float v = tb[r * DF + (ch << 6) + cc];
    if (us) v = simple_tf(v, Cg);
    GBUF[r * 68 + cc] = v;
  }
}

// =====================================================================
// qp_kernel: TWO batches per 640-thread block (waves 0-4 / 5-9), grid
// B/2 = 256 -> exactly 1 block/CU, 10 waves resident. This is the
// PROVEN structure (R0, 446.8us); all structural variants (320-blocks,
// fused tail, LDS atomics, flag barriers, column-ownership) regressed.
// Deltas vs R0: phase-1 deleted (norms from raw Gram diagonal), fdrcp
// in GJ pivots + dd/di, write-first W accumulation.
// =====================================================================
__global__ void __launch_bounds__(TPB) qp_kernel(
    const float* __restrict__ train, const int* __restrict__ usimple,
    float* __restrict__ xfg, const int B) {
  const int tid = threadIdx.x;
  const int half = tid >= 320 ? 1 : 0;
  const int tl = tid - 320 * half;
  const int lane = tid & 63;
  const int w = tl >> 6;
  const int bb = 2 * blockIdx.x + half;
  const bool live = bb < B;
  const bool us = (usimple[0] != 0);
  const float Cg = gfun(1e-5f);

  __shared__ double Msh_[2][650];
  __shared__ __align__(16) unsigned char GBW_[2][6800];
  __shared__ double x_[2][125], s_[2][125], z_[2][125], rx_[2][125],
      rz_[2][125], dd_[2][125], di_[2][125], tt_[2][125], c1_[2][125],
      vv_[2][125], dxa_[2][125], dsa_[2][125], dza_[2][125], rsc_[2][125];
  __shared__ double yv_[2][25], ry_[2][25], c2_[2][25], gg_[2][25],
      dya_[2][25], dyw_[2][25];
  __shared__ double SC_[2][16];
  __shared__ float invn_[2][25];
  __shared__ float bxs_[2][125];

  double* Msh = Msh_[half];
  double* W = (double*)GBW_[half];
  float* GBUF = (float*)GBW_[half];
  double* x = x_[half];
  double* sv = s_[half];
  double* zv = z_[half];
  double* rx = rx_[half];
  double* rz = rz_[half];
  double* dd = dd_[half];
  double* di = di_[half];
  double* tt = tt_[half];
  double* c1 = c1_[half];
  double* vv = vv_[half];
  double* dxa = dxa_[half];
  double* dsa = dsa_[half];
  double* dza = dza_[half];
  double* rsc = rsc_[half];
  double* yv = yv_[half];
  double* ry = ry_[half];
  double* c2 = c2_[half];
  double* gg = gg_[half];
  double* dya = dya_[half];
  double* dyw = dyw_[half];
  double* SC = SC_[half];
  float* invn = invn_[half];
  float* bxs = bxs_[half];
  double* dinvn = c2;  // c2 is dead until the first kkt_solve
  double hv[25];

  const float* tb = train + (size_t)(live ? bb : 0) * NSUP * DF;

  // ---- phase 2: chunked RAW Gram G = F F^T (fp64 accumulate) ----
  int i1, j1, i2v = 0, j2v = 0;
  {
    int rem = tl, i = 0;
    while (rem >= NSUP - i) { rem -= NSUP - i; ++i; }
    i1 = i; j1 = i + rem;
  }
  if (tl < 5) {
    int rem = 320 + tl, i = 0;
    while (rem >= NSUP - i) { rem -= NSUP - i; ++i; }
    i2v = i; j2v = i + rem;
  }
  double acc1 = 0.0, acc2 = 0.0;
  for (int ch = 0; ch < 10; ++ch) {
    stage_chunk(tb, ch, us, Cg, GBUF, tl);
    __syncthreads();
    {
      const float4* ra = (const float4*)(GBUF + i1 * 68);
      const float4* rb = (const float4*)(GBUF + j1 * 68);
#pragma unroll
      for (int c = 0; c < 16; ++c) {
        float4 av = ra[c], bv = rb[c];
        acc1 += (double)av.x * bv.x + (double)av.y * bv.y +
                (double)av.z * bv.z + (double)av.w * bv.w;
      }
    }
    if (tl < 5) {
      const float4* ra = (const float4*)(GBUF + i2v * 68);
      const float4* rb = (const float4*)(GBUF + j2v * 68);
#pragma unroll
      for (int c = 0; c < 16; ++c) {
        float4 av = ra[c], bv = rb[c];
        acc2 += (double)av.x * bv.x + (double)av.y * bv.y +
                (double)av.z * bv.z + (double)av.w * bv.w;
      }
    }
    __syncthreads();
  }
  Msh[i1 * 26 + j1] = acc1;
  if (i1 != j1) Msh[j1 * 26 + i1] = acc1;
  if (tl < 5) {
    Msh[i2v * 26 + j2v] = acc2;
    if (i2v != j2v) Msh[j2v * 26 + i2v] = acc2;
  }
  __syncthreads();

  // ---- norms from Gram diagonal; rescale M = D G D + I ----
  if (tl < 25) {
    const double g = Msh[tl * 27];
    const double dn = 1.0 / fmax(sqrt(g), 1e-12);
    dinvn[tl] = dn;
    invn[tl] = (float)dn;
  }
  __syncthreads();
  for (int idx = tl; idx < 650; idx += 320) {
    const int i = idx / 26, j = idx - i * 26;
    if (j < 25) {
      double v = Msh[idx] * dinvn[i] * dinvn[j];
      if (i == j) v += 1.0;
      Msh[idx] = v;
    }
  }

  // ---- phase 3: QP init ----
  if (tl < NZV) {
    const int i = tl / 5, k = tl - i * 5;
    const double oh = (k == (i % 5)) ? 1.0 : 0.0;
    rx[tl] = -oh;
    rz[tl] = -0.1 * oh;
    dd[tl] = 1.0;
    di[tl] = 1.0;
  } else if (tl >= 128 && tl < 153) {
    ry[tl - 128] = 0.0;
  }
  if (tl == 0) SC[0] = 1e300;
  __syncthreads();

  factorize(Msh, dd, W, hv, tl, lane, w);
  kkt_solve<true, false, false>(Msh, dd, di, tt, c1, c2, vv, gg, dyw, rx,
                                (const double*)nullptr, rz, ry, hv, x, sv, zv,
                                yv, tl, lane, w);
  {
    const double ms = bred(sv, NZV, 1, SC, w, lane);
    if (ms < 0.0 && tl < NZV) sv[tl] -= (ms - 1.0);
    const double mz = bred(zv, NZV, 1, SC, w, lane);
    if (mz < 0.0 && tl < NZV) zv[tl] -= (mz - 1.0);
  }
  if (tl < NZV) bxs[tl] = (float)x[tl];

#pragma unroll 1
  for (int it = 0; it < 3; ++it) {
    __syncthreads();
    if (tl < NZV) {
      const int i = tl / 5, k = tl - i * 5;
      double acc = 0.0;
#pragma unroll
      for (int j = 0; j < 25; ++j) acc += Msh[i * 26 + j] * x[j * 5 + k];
      const double oh = (k == (i % 5)) ? 1.0 : 0.0;
      rx[tl] = yv[i] + zv[tl] + acc - oh;
      rz[tl] = x[tl] + sv[tl] - 0.1 * oh;
    } else if (tl >= 128 && tl < 153) {
      const int i = tl - 128;
      double acc = 0.0;
#pragma unroll
      for (int k = 0; k < 5; ++k) acc += x[i * 5 + k];
      ry[i] = acc;
    }
    __syncthreads();
    if (w == 0) {  // per-half consolidated 4-sum reduction (first wave)
      double s1 = 0, s2 = 0, s3 = 0, s4 = 0;
      for (int m = lane; m < 125; m += 64) {
        s1 += sv[m] * zv[m];
        s2 += rx[m] * rx[m];
        s3 += rz[m] * rz[m];
      }
      if (lane < 25) s4 = ry[lane] * ry[lane];
#pragma unroll
      for (int off = 32; off > 0; off >>= 1) {
        s1 += __shfl_xor(s1, off);
        s2 += __shfl_xor(s2, off);
        s3 += __shfl_xor(s3, off);
        s4 += __shfl_xor(s4, off);
      }
      if (lane == 0) { SC[2] = s1; SC[3] = s2; SC[4] = s3; SC[5] = s4; }
    }
    __syncthreads();
    const double szsum = SC[2];
    const double mu = fabs(szsum) / 125.0;
    const double res = sqrt(SC[4] + 1e-30) + sqrt(SC[5] + 1e-30) +
                       sqrt(SC[3] + 1e-30) + 125.0 * mu;
    if (tl == 0) {
      if (res < SC[0]) { SC[0] = res; SC[1] = 1.0; } else SC[1] = 0.0;
    }
    __syncthreads();
    if (SC[1] != 0.0 && tl < NZV) bxs[tl] = (float)x[tl];
    if (it == 2) break;
    __syncthreads();

    if (tl < NZV) {
      dd[tl] = zv[tl] * fdrcp(sv[tl]);
      di[tl] = sv[tl] * fdrcp(zv[tl]);
    }
    __syncthreads();
    factorize(Msh, dd, W, hv, tl, lane, w);
    kkt_solve<false, false, false>(Msh, dd, di, tt, c1, c2, vv, gg, dyw, rx,
                                   zv, rz, ry, hv, dxa, dsa, dza, dya, tl,
                                   lane, w);
    if (tl < NZV) {
      const double a1 = (dza[tl] < 0.0) ? (-zv[tl] / dza[tl]) : 1e12;
      const double a2 = (dsa[tl] < 0.0) ? (-sv[tl] / dsa[tl]) : 1e12;
      tt[tl] = fmin(a1, a2);
    }
    const double aff = fmin(bred(tt, NZV, 1, SC, w, lane), 1.0);
    if (tl < NZV)
      tt[tl] = (sv[tl] + aff * dsa[tl]) * (zv[tl] + aff * dza[tl]);
    const double num = bred(tt, NZV, 0, SC, w, lane);
    const double sg = num / szsum;
    const double musig = mu * (sg * sg * sg);
    if (tl < NZV) rsc[tl] = (-musig + dsa[tl] * dza[tl]) * fdrcp(sv[tl]);
    __syncthreads();
    kkt_solve<false, true, true>(Msh, dd, di, tt, c1, c2, vv, gg, dyw, rx,
                                 rsc, rz, ry, hv, dxa, dsa, dza, dya, tl,
                                 lane, w);
    if (tl < NZV) {
      const double a1 = (dza[tl] < 0.0) ? (-zv[tl] / dza[tl]) : 1e12;
      const double a2 = (dsa[tl] < 0.0) ? (-sv[tl] / dsa[tl]) : 1e12;
      tt[tl] = fmin(a1, a2);
    }
    const double al = fmin(0.999 * bred(tt, NZV, 1, SC, w, lane), 1.0);
    if (tl < NZV) {
      x[tl] += al * dxa[tl];
      sv[tl] += al * dsa[tl];
      zv[tl] += al * dza[tl];
    } else if (tl >= 128 && tl < 153) {
      const int i = tl - 128;
      yv[i] += al * dya[i];
    }
  }
  __syncthreads();

  // ---- phase 4: xfg[w][d] = sum_s (bx[s,w]*invn[s]) * Fraw[s][d] ----
  float xs[25];
#pragma unroll
  for (int s_ = 0; s_ < 25; ++s_) xs[s_] = bxs[s_ * 5 + w] * invn[s_];
  for (int ch = 0; ch < 10; ++ch) {
    stage_chunk(tb, ch, us, Cg, GBUF, tl);
    __syncthreads();
    float acc = 0.0f;
#pragma unroll
    for (int s_ = 0; s_ < 25; ++s_) acc += xs[s_] * GBUF[s_ * 68 + lane];
    if (live)
      xfg[((size_t)bb * NWAY + w) * DF + (ch << 6) + lane] = acc;
    __syncthreads();
  }
}

// =====================================================================
// Output kernel: TWO blocks per batch (even/odd queries) -> grid 2B =
// 1024 blocks, small LDS (12.8 KB) so blocks co-reside and the
// latency-bound tail actually hides. float4 loads (3/query).
// =====================================================================
__global__ void __launch_bounds__(640) out_kernel(
    const float* __restrict__ test, const int* __restrict__ usimple,
    const float* __restrict__ xfg, float* __restrict__ out) {
  const int bid = blockIdx.x;
  const int b = bid >> 1;
  const int hh = bid & 1;   // even / odd queries
  const int tid = threadIdx.x;
  const int lane = tid & 63;
  const int u = tid >> 6;   // 0..9
  const bool us = (usimple[0] != 0);
  const float Cg = gfun(1e-5f);

  __shared__ float xfs[NWAY * DF];
  for (int i = tid; i < NWAY * DF; i += 640)
    xfs[i] = xfg[(size_t)b * NWAY * DF + i];
  __syncthreads();
  const float4* xf4 = (const float4*)xfs;

  const float* qb = test + (size_t)b * NQ * DF;
#pragma unroll 2
  for (int jj = 0; jj < 4; ++jj) {
    const int q = 2 * (u + 10 * jj) + hh;
    if (q >= NQ) break;  // q monotone in jj
    const float4* qr4 = (const float4*)(qb + (size_t)q * DF);
    float nrm = 0.0f, a0 = 0.0f, a1 = 0.0f, a2 = 0.0f, a3 = 0.0f, a4 = 0.0f;
#pragma unroll
    for (int c = 0; c < 3; ++c) {
      if (c < 2 || lane < 32) {
        const int f4i = lane + 64 * c;
        float4 vq = qr4[f4i];
        if (us) {
          vq.x = simple_tf(vq.x, Cg);
          vq.y = simple_tf(vq.y, Cg);
          vq.z = simple_tf(vq.z, Cg);
          vq.w = simple_tf(vq.w, Cg);
        }
        nrm += vq.x * vq.x + vq.y * vq.y + vq.z * vq.z + vq.w * vq.w;
        float4 t;
        t = xf4[0 * (DF / 4) + f4i];
        a0 += vq.x * t.x + vq.y * t.y + vq.z * t.z + vq.w * t.w;
        t = xf4[1 * (DF / 4) + f4i];
        a1 += vq.x * t.x + vq.y * t.y + vq.z * t.z + vq.w * t.w;
        t = xf4[2 * (DF / 4) + f4i];
        a2 += vq.x * t.x + vq.y * t.y + vq.z * t.z + vq.w * t.w;
        t = xf4[3 * (DF / 4) + f4i];
        a3 += vq.x * t.x + vq.y * t.y + vq.z * t.z + vq.w * t.w;
        t = xf4[4 * (DF / 4) + f4i];
        a4 += vq.x * t.x + vq.y * t.y + vq.z * t.z + vq.w * t.w;
      }
    }
#pragma unroll
    for (int off = 32; off > 0; off >>= 1) {
      nrm += __shfl_xor(nrm, off);
      a0 += __shfl_xor(a0, off);
      a1 += __shfl_xor(a1, off);
      a2 += __shfl_xor(a2, off);
      a3 += __shfl_xor(a3, off);
      a4 += __shfl_xor(a4, off);
    }
    if (lane == 0) {
      const float sc = 1.0f / fmaxf(sqrtf(nrm), 1e-12f);
      float* op = out + ((size_t)b * NQ + q) * 5;
      op[0] = a0 * sc;
      op[1] = a1 * sc;
      op[2] = a2 * sc;
      op[3] = a3 * sc;
      op[4] = a4 * sc;
    }
  }
}

// =====================================================================
extern "C" void kernel_launch(void* const* d_in, const int* in_sizes, int n_in,
                              void* d_out, int out_size, void* d_ws,
                              size_t ws_size, hipStream_t stream) {
  const float* ftest = (const float*)d_in[0];
  const float* ftrain = (const float*)d_in[1];
  const int* usimple = (const int*)d_in[4];
  float* out = (float*)d_out;
  const int B = in_sizes[1] / (NSUP * DF);

  float* xfg = (float*)d_ws;  // B * 5 * 640 floats

  qp_kernel<<<dim3((B + 1) / 2), dim3(TPB), 0, stream>>>(ftrain, usimple,
                                                         xfg, B);
  out_kernel<<<dim3(2 * B), dim3(640), 0, stream>>>(ftest, usimple, xfg,
                                                    out);
}